// Round 1
// baseline (301.254 us; speedup 1.0000x reference)
//
#include <hip/hip_runtime.h>

typedef short short8 __attribute__((ext_vector_type(8)));
typedef float f32x4 __attribute__((ext_vector_type(4)));

#define LOG2E 1.44269504088896340736f

__device__ __forceinline__ unsigned short f2bf(float f) {
  unsigned u = __builtin_bit_cast(unsigned, f);
  u += 0x7fffu + ((u >> 16) & 1u);
  return (unsigned short)(u >> 16);
}

__device__ __forceinline__ void gload16(const void* g, void* l) {
  typedef __attribute__((address_space(1))) unsigned int gas;
  typedef __attribute__((address_space(3))) unsigned int las;
  __builtin_amdgcn_global_load_lds((gas*)(unsigned long long)g,
                                   (las*)(unsigned)(unsigned long long)l, 16, 0, 0);
}

#define MFMA16(a, b, c) __builtin_amdgcn_mfma_f32_16x16x32_bf16(a, b, c, 0, 0, 0)

// ---------------------------------------------------------------- weights ----
// W fp32 [1024 k][1024 n] -> Wt bf16 [1024 n][1024 k]  (4 matrices)
__global__ __launch_bounds__(256) void wtrans_kernel(
    const float* __restrict__ Wq, const float* __restrict__ Wk,
    const float* __restrict__ Wv, const float* __restrict__ Wo,
    unsigned short* __restrict__ Wt) {
  const int wsel = blockIdx.z;
  const float* W = wsel == 0 ? Wq : wsel == 1 ? Wk : wsel == 2 ? Wv : Wo;
  unsigned short* out = Wt + (long)wsel * 1048576;
  __shared__ float lds[64][65];
  const int t = threadIdx.x;
  const int k0 = blockIdx.x * 64, n0 = blockIdx.y * 64;
#pragma unroll
  for (int i = 0; i < 4; ++i) {
    int r = (t >> 4) + i * 16, c4 = (t & 15) * 4;
    float4 vv = *(const float4*)(W + (long)(k0 + r) * 1024 + n0 + c4);
    lds[r][c4] = vv.x; lds[r][c4 + 1] = vv.y; lds[r][c4 + 2] = vv.z; lds[r][c4 + 3] = vv.w;
  }
  __syncthreads();
#pragma unroll
  for (int i = 0; i < 16; ++i) {
    int flat = t + i * 256;
    int n = flat >> 6, kk = flat & 63;
    out[(long)(n0 + n) * 1024 + k0 + kk] = f2bf(lds[kk][n]);
  }
}

// ---------------------------------------------------------------- mask pack --
// mask int32 [B,1,S,S] -> bits [B][S][S/32]
__global__ __launch_bounds__(256) void maskpack_kernel(const int* __restrict__ mask,
                                                       unsigned* __restrict__ bits) {
  const long n = 8388608;  // 2*2048*2048
  const long stride = (long)gridDim.x * 256;
  const int lane = threadIdx.x & 63;
  for (long i = (long)blockIdx.x * 256 + threadIdx.x; i < n; i += stride) {
    unsigned long long bal = __ballot(mask[i] != 0);
    if ((lane & 31) == 0) bits[i >> 5] = (unsigned)(bal >> (lane & 32));
  }
}

// ---------------------------------------------------------------- layernorm --
__global__ __launch_bounds__(256) void ln_kernel(
    const float* __restrict__ q, const float* __restrict__ k, const float* __restrict__ v,
    const float* __restrict__ gamma, const float* __restrict__ beta,
    unsigned short* __restrict__ lnq, unsigned short* __restrict__ lnk,
    unsigned short* __restrict__ lnv) {
  const int row = blockIdx.x, which = blockIdx.y;
  const float* x = (which == 0 ? q : which == 1 ? k : v) + (long)row * 1024;
  unsigned short* y = (which == 0 ? lnq : which == 1 ? lnk : lnv) + (long)row * 1024;
  const int t = threadIdx.x, lane = t & 63, wv = t >> 6;
  float4 xv = ((const float4*)x)[t];
  float s = xv.x + xv.y + xv.z + xv.w;
  float s2 = xv.x * xv.x + xv.y * xv.y + xv.z * xv.z + xv.w * xv.w;
#pragma unroll
  for (int off = 32; off > 0; off >>= 1) {
    s += __shfl_down(s, off);
    s2 += __shfl_down(s2, off);
  }
  __shared__ float red[8];
  if (lane == 0) { red[wv] = s; red[wv + 4] = s2; }
  __syncthreads();
  float tot = red[0] + red[1] + red[2] + red[3];
  float tot2 = red[4] + red[5] + red[6] + red[7];
  float mu = tot * (1.0f / 1024.0f);
  float var = tot2 * (1.0f / 1024.0f) - mu * mu;
  float rs = rsqrtf(var + 1e-5f);
  float4 g = ((const float4*)gamma)[t];
  float4 be = ((const float4*)beta)[t];
  ushort4 o;
  o.x = f2bf((xv.x - mu) * rs * g.x + be.x);
  o.y = f2bf((xv.y - mu) * rs * g.y + be.y);
  o.z = f2bf((xv.z - mu) * rs * g.z + be.z);
  o.w = f2bf((xv.w - mu) * rs * g.w + be.w);
  ((ushort4*)y)[t] = o;
}

// ---------------------------------------------------------------- GEMM -------
// C[M=4096, N=1024] = A(bf16 [m][1024]) @ Bt(bf16 [n][1024])^T + bias
// MODE 0: bf16 out in heads layout [B,H,S,64]; MODE 1: fp32 out row-major.
template <int BM, int MODE>
__global__ __launch_bounds__(256) void gemm_kernel(
    const unsigned short* __restrict__ A0, const unsigned short* __restrict__ A1,
    const unsigned short* __restrict__ A2, const unsigned short* __restrict__ Wt,
    const float* __restrict__ b0, const float* __restrict__ b1,
    const float* __restrict__ b2, unsigned short* __restrict__ outB,
    float* __restrict__ outF) {
  constexpr int BK = 64;
  constexpr int MI = BM / 32;  // m-frags per wave
  const int z = blockIdx.z;
  const unsigned short* A = z == 0 ? A0 : z == 1 ? A1 : A2;
  const unsigned short* Bt = Wt + (long)z * 1048576;
  const float* bias = z == 0 ? b0 : z == 1 ? b1 : b2;
  unsigned short* outz = outB + (long)z * 4194304;

  __shared__ char lds[BM * 128 + 16384];
  char* As = lds;
  char* Bs = lds + BM * 128;
  const int tid = threadIdx.x, lane = tid & 63, w = tid >> 6;
  const int wr = w >> 1, wc = w & 1;
  const int m0 = blockIdx.x * BM, n0 = blockIdx.y * 128;
  constexpr int K = 1024;
  constexpr int ACH = BM * 8 / 256;

  f32x4 acc[MI][4] = {};
  for (int kt = 0; kt < K / BK; ++kt) {
    __syncthreads();
#pragma unroll
    for (int i = 0; i < ACH; ++i) {
      int c = tid + i * 256;
      int row = c >> 3, pg = (c & 7) ^ (row & 7);
      gload16(A + (long)(m0 + row) * K + kt * BK + pg * 8, As + c * 16);
    }
#pragma unroll
    for (int i = 0; i < 4; ++i) {
      int c = tid + i * 256;
      int row = c >> 3, pg = (c & 7) ^ (row & 7);
      gload16(Bt + (long)(n0 + row) * K + kt * BK + pg * 8, Bs + c * 16);
    }
    asm volatile("s_waitcnt vmcnt(0)" ::: "memory");
    __syncthreads();
#pragma unroll
    for (int ks = 0; ks < 2; ++ks) {
      short8 af[MI], bf[4];
#pragma unroll
      for (int mi = 0; mi < MI; ++mi) {
        int row = wr * (BM / 2) + mi * 16 + (lane & 15);
        int part = (ks * 4 + (lane >> 4)) ^ (row & 7);
        af[mi] = *(const short8*)(As + row * 128 + part * 16);
      }
#pragma unroll
      for (int ni = 0; ni < 4; ++ni) {
        int row = wc * 64 + ni * 16 + (lane & 15);
        int part = (ks * 4 + (lane >> 4)) ^ (row & 7);
        bf[ni] = *(const short8*)(Bs + row * 128 + part * 16);
      }
#pragma unroll
      for (int mi = 0; mi < MI; ++mi)
#pragma unroll
        for (int ni = 0; ni < 4; ++ni)
          acc[mi][ni] = MFMA16(af[mi], bf[ni], acc[mi][ni]);
    }
  }
  // epilogue
#pragma unroll
  for (int mi = 0; mi < MI; ++mi) {
    int mbase = m0 + wr * (BM / 2) + mi * 16 + ((lane >> 4) << 2);
#pragma unroll
    for (int ni = 0; ni < 4; ++ni) {
      int j = n0 + wc * 64 + ni * 16 + (lane & 15);
      float bj = bias[j];
#pragma unroll
      for (int r = 0; r < 4; ++r) {
        float vv = acc[mi][ni][r] + bj;
        int mm = mbase + r;
        if (MODE == 0) {
          int b = mm >> 11, s = mm & 2047;
          int h = j >> 6, d = j & 63;
          outz[(((long)(b * 16 + h)) * 2048 + s) * 64 + d] = f2bf(vv);
        } else {
          outF[(long)mm * 1024 + j] = vv;
        }
      }
    }
  }
}

// ---------------------------------------------------------------- V transpose
// vh bf16 [BH][2048][64] -> vt bf16 [BH][64][2048]
__global__ __launch_bounds__(256) void vtrans_kernel(const unsigned short* __restrict__ vh,
                                                     unsigned short* __restrict__ vt) {
  const int bh = blockIdx.y, s0 = blockIdx.x * 64;
  const unsigned short* in = vh + (long)bh * 2048 * 64;
  unsigned short* out = vt + (long)bh * 64 * 2048;
  __shared__ unsigned short lds[64][72];
  const int t = threadIdx.x;
#pragma unroll
  for (int i = 0; i < 2; ++i) {
    int c = t + i * 256;
    int sl = c >> 3, p = c & 7;
    short8 vv = *(const short8*)(in + (long)(s0 + sl) * 64 + p * 8);
#pragma unroll
    for (int j = 0; j < 8; ++j) lds[sl][p * 8 + j] = (unsigned short)vv[j];
  }
  __syncthreads();
#pragma unroll
  for (int i = 0; i < 4; ++i) {
    int c = t + i * 256;
    int d = c >> 4, s4 = (c & 15) * 4;
    ushort4 o;
    o.x = lds[s4][d]; o.y = lds[s4 + 1][d]; o.z = lds[s4 + 2][d]; o.w = lds[s4 + 3][d];
    *(ushort4*)(out + (long)d * 2048 + s0 + s4) = o;
  }
}

// ---------------------------------------------------------------- attention --
// qh,kh [BH][2048][64] bf16; vt [BH][64][2048] bf16; mbits [B][2048][64] u32
// O [BH][2048][64] bf16 (flash, BQ=128 per block, BKV=128 per k-tile, 4 waves)
__global__ __launch_bounds__(256) void attn_kernel(
    const unsigned short* __restrict__ qh, const unsigned short* __restrict__ kh,
    const unsigned short* __restrict__ vt, const unsigned* __restrict__ mbits,
    unsigned short* __restrict__ O) {
  constexpr int S = 2048;
  __shared__ char lds[65536];  // Ks 16K | Vts 16K | P 4x8K
  char* Ks = lds;
  char* Vts = lds + 16384;
  const int tid = threadIdx.x, lane = tid & 63, w = tid >> 6;
  char* Pw = lds + 32768 + w * 8192;
  const int bh = blockIdx.y, b = bh >> 4;
  const unsigned short* qp = qh + (long)bh * S * 64;
  const unsigned short* kp = kh + (long)bh * S * 64;
  const unsigned short* vp = vt + (long)bh * 64 * S;
  unsigned short* op = O + (long)bh * S * 64;
  const unsigned* mrow = mbits + (long)b * S * 64;
  const int q0 = blockIdx.x * 128 + w * 32;

  short8 aq[2][2];
#pragma unroll
  for (int mi = 0; mi < 2; ++mi)
#pragma unroll
    for (int ds = 0; ds < 2; ++ds)
      aq[mi][ds] = *(const short8*)(qp + (long)(q0 + mi * 16 + (lane & 15)) * 64 +
                                    ds * 32 + (lane >> 4) * 8);

  f32x4 o_acc[2][4] = {};
  float m_run[2][4], l_run[2][4];
#pragma unroll
  for (int mi = 0; mi < 2; ++mi)
#pragma unroll
    for (int r = 0; r < 4; ++r) { m_run[mi][r] = -3.0e38f; l_run[mi][r] = 0.f; }

  for (int kt = 0; kt < S / 128; ++kt) {
    __syncthreads();
#pragma unroll
    for (int i = 0; i < 4; ++i) {  // K tile [128][64], 8 parts/row swizzled
      int c = tid + i * 256;
      int row = c >> 3, pg = (c & 7) ^ (row & 7);
      gload16(kp + (long)(kt * 128 + row) * 64 + pg * 8, Ks + c * 16);
    }
#pragma unroll
    for (int i = 0; i < 4; ++i) {  // Vt tile [64][128], 16 parts/row swizzled
      int c = tid + i * 256;
      int row = c >> 4, pg = (c & 15) ^ (row & 15);
      gload16(vp + (long)row * S + kt * 128 + pg * 8, Vts + c * 16);
    }
    asm volatile("s_waitcnt vmcnt(0)" ::: "memory");
    __syncthreads();

    // QK^T
    f32x4 sc[2][8] = {};
#pragma unroll
    for (int ds = 0; ds < 2; ++ds) {
      short8 bk[8];
#pragma unroll
      for (int ki = 0; ki < 8; ++ki) {
        int row = ki * 16 + (lane & 15);
        int part = (ds * 4 + (lane >> 4)) ^ (row & 7);
        bk[ki] = *(const short8*)(Ks + row * 128 + part * 16);
      }
#pragma unroll
      for (int mi = 0; mi < 2; ++mi)
#pragma unroll
        for (int ki = 0; ki < 8; ++ki) sc[mi][ki] = MFMA16(aq[mi][ds], bk[ki], sc[mi][ki]);
    }

    // mask + online softmax + P write
#pragma unroll
    for (int mi = 0; mi < 2; ++mi) {
#pragma unroll
      for (int r = 0; r < 4; ++r) {
        int qrow = q0 + mi * 16 + (lane >> 4) * 4 + r;
        uint4 mw = *(const uint4*)(mrow + (long)qrow * 64 + kt * 4);
        unsigned wsel[4] = {mw.x, mw.y, mw.z, mw.w};
        float s[8];
        float tmax = -3.0e38f;
#pragma unroll
        for (int ki = 0; ki < 8; ++ki) {
          unsigned bit = ((ki & 1) << 4) | (lane & 15);
          bool live = (wsel[ki >> 1] >> bit) & 1u;
          float sv = sc[mi][ki][r];
          sv = live ? sv * 0.125f : -1.25e19f;
          s[ki] = sv;
          tmax = fmaxf(tmax, sv);
        }
#pragma unroll
        for (int off = 1; off < 16; off <<= 1) tmax = fmaxf(tmax, __shfl_xor(tmax, off));
        float mnew = fmaxf(m_run[mi][r], tmax);
        float fac = exp2f((m_run[mi][r] - mnew) * LOG2E);
        float rsum = 0.f;
        int prow = mi * 16 + (lane >> 4) * 4 + r;
#pragma unroll
        for (int ki = 0; ki < 8; ++ki) {
          float p = exp2f((s[ki] - mnew) * LOG2E);
          rsum += p;
          int col = ki * 16 + (lane & 15);
          int part = (col >> 3) ^ (prow & 15);
          *(unsigned short*)(Pw + prow * 256 + part * 16 + (col & 7) * 2) = f2bf(p);
        }
#pragma unroll
        for (int off = 1; off < 16; off <<= 1) rsum += __shfl_xor(rsum, off);
        l_run[mi][r] = l_run[mi][r] * fac + rsum;
        m_run[mi][r] = mnew;
#pragma unroll
        for (int nd = 0; nd < 4; ++nd) o_acc[mi][nd][r] *= fac;
      }
    }
    asm volatile("s_waitcnt lgkmcnt(0)" ::: "memory");
    __builtin_amdgcn_sched_barrier(0);

    // PV
#pragma unroll
    for (int ks = 0; ks < 4; ++ks) {
      short8 pa[2], bv[4];
#pragma unroll
      for (int mi = 0; mi < 2; ++mi) {
        int prow = mi * 16 + (lane & 15);
        int part = (ks * 4 + (lane >> 4)) ^ (prow & 15);
        pa[mi] = *(const short8*)(Pw + prow * 256 + part * 16);
      }
#pragma unroll
      for (int nd = 0; nd < 4; ++nd) {
        int row = nd * 16 + (lane & 15);
        int part = (ks * 4 + (lane >> 4)) ^ (row & 15);
        bv[nd] = *(const short8*)(Vts + row * 256 + part * 16);
      }
#pragma unroll
      for (int mi = 0; mi < 2; ++mi)
#pragma unroll
        for (int nd = 0; nd < 4; ++nd) o_acc[mi][nd] = MFMA16(pa[mi], bv[nd], o_acc[mi][nd]);
    }
  }
  // epilogue: O /= l
#pragma unroll
  for (int mi = 0; mi < 2; ++mi) {
#pragma unroll
    for (int r = 0; r < 4; ++r) {
      int qrow = q0 + mi * 16 + (lane >> 4) * 4 + r;
      float inv = 1.0f / l_run[mi][r];
#pragma unroll
      for (int nd = 0; nd < 4; ++nd) {
        int d = nd * 16 + (lane & 15);
        op[(long)qrow * 64 + d] = f2bf(o_acc[mi][nd][r] * inv);
      }
    }
  }
}

// ---------------------------------------------------------------- launch -----
extern "C" void kernel_launch(void* const* d_in, const int* in_sizes, int n_in,
                              void* d_out, int out_size, void* d_ws, size_t ws_size,
                              hipStream_t stream) {
  const float* q = (const float*)d_in[0];
  const float* k = (const float*)d_in[1];
  const float* v = (const float*)d_in[2];
  const int* mask = (const int*)d_in[3];
  const float* Wq = (const float*)d_in[4];
  const float* bq = (const float*)d_in[5];
  const float* Wk = (const float*)d_in[6];
  const float* bk = (const float*)d_in[7];
  const float* Wv = (const float*)d_in[8];
  const float* bv = (const float*)d_in[9];
  const float* Wo = (const float*)d_in[10];
  const float* bo = (const float*)d_in[11];
  const float* gamma = (const float*)d_in[12];
  const float* beta = (const float*)d_in[13];
  float* out = (float*)d_out;

  char* ws = (char*)d_ws;
  unsigned short* Wt = (unsigned short*)ws;                         // 8 MB (4x 1M bf16)
  unsigned* mbits = (unsigned*)(ws + 8u * 1024 * 1024);             // 1 MB
  unsigned short* lnq = (unsigned short*)(ws + 9u * 1024 * 1024);   // 8 MB
  unsigned short* lnk = lnq + 4194304;                              // 8 MB
  unsigned short* lnv = lnk + 4194304;                              // 8 MB
  unsigned short* qh = lnv + 4194304;                               // 8 MB
  unsigned short* kh = qh + 4194304;                                // 8 MB
  unsigned short* vh = kh + 4194304;                                // 8 MB
  unsigned short* vtb = lnk;  // alias: lnk dead after QKV GEMM
  unsigned short* Ob = lnq;   // alias: lnq dead after QKV GEMM

  wtrans_kernel<<<dim3(16, 16, 4), 256, 0, stream>>>(Wq, Wk, Wv, Wo, Wt);
  maskpack_kernel<<<1024, 256, 0, stream>>>(mask, mbits);
  ln_kernel<<<dim3(4096, 3), 256, 0, stream>>>(q, k, v, gamma, beta, lnq, lnk, lnv);
  gemm_kernel<128, 0><<<dim3(32, 8, 3), 256, 0, stream>>>(lnq, lnk, lnv, Wt, bq, bk, bv,
                                                          qh, nullptr);
  vtrans_kernel<<<dim3(32, 32), 256, 0, stream>>>(vh, vtb);
  attn_kernel<<<dim3(16, 32), 256, 0, stream>>>(qh, kh, vtb, mbits, Ob);
  gemm_kernel<64, 1><<<dim3(64, 8, 1), 256, 0, stream>>>(Ob, Ob, Ob, Wt + 3 * 1048576,
                                                         bo, bo, bo, nullptr, out);
}

// Round 2
// 179.076 us; speedup vs baseline: 1.6823x; 1.6823x over previous
//
#include <hip/hip_runtime.h>

typedef short short8 __attribute__((ext_vector_type(8)));
typedef float f32x4 __attribute__((ext_vector_type(4)));

#define LOG2E 1.44269504088896340736f

__device__ __forceinline__ unsigned short f2bf(float f) {
  unsigned u = __builtin_bit_cast(unsigned, f);
  u += 0x7fffu + ((u >> 16) & 1u);
  return (unsigned short)(u >> 16);
}

__device__ __forceinline__ void gload16(const void* g, void* l) {
  typedef __attribute__((address_space(1))) unsigned int gas;
  typedef __attribute__((address_space(3))) unsigned int las;
  __builtin_amdgcn_global_load_lds((gas*)(unsigned long long)g,
                                   (las*)(unsigned)(unsigned long long)l, 16, 0, 0);
}

#define MFMA16(a, b, c) __builtin_amdgcn_mfma_f32_16x16x32_bf16(a, b, c, 0, 0, 0)

// ---------------------------------------------------------------- weights ----
__global__ __launch_bounds__(256) void wtrans_kernel(
    const float* __restrict__ Wq, const float* __restrict__ Wk,
    const float* __restrict__ Wv, const float* __restrict__ Wo,
    unsigned short* __restrict__ Wt) {
  const int wsel = blockIdx.z;
  const float* W = wsel == 0 ? Wq : wsel == 1 ? Wk : wsel == 2 ? Wv : Wo;
  unsigned short* out = Wt + (long)wsel * 1048576;
  __shared__ float lds[64][65];
  const int t = threadIdx.x;
  const int k0 = blockIdx.x * 64, n0 = blockIdx.y * 64;
#pragma unroll
  for (int i = 0; i < 4; ++i) {
    int r = (t >> 4) + i * 16, c4 = (t & 15) * 4;
    float4 vv = *(const float4*)(W + (long)(k0 + r) * 1024 + n0 + c4);
    lds[r][c4] = vv.x; lds[r][c4 + 1] = vv.y; lds[r][c4 + 2] = vv.z; lds[r][c4 + 3] = vv.w;
  }
  __syncthreads();
#pragma unroll
  for (int i = 0; i < 16; ++i) {
    int flat = t + i * 256;
    int n = flat >> 6, kk = flat & 63;
    out[(long)(n0 + n) * 1024 + k0 + kk] = f2bf(lds[kk][n]);
  }
}

// ---------------------------------------------------------------- mask pack --
__global__ __launch_bounds__(256) void maskpack_kernel(const int* __restrict__ mask,
                                                       unsigned* __restrict__ bits) {
  const long n = 8388608;  // 2*2048*2048
  const long stride = (long)gridDim.x * 256;
  const int lane = threadIdx.x & 63;
  for (long i = (long)blockIdx.x * 256 + threadIdx.x; i < n; i += stride) {
    unsigned long long bal = __ballot(mask[i] != 0);
    if ((lane & 31) == 0) bits[i >> 5] = (unsigned)(bal >> (lane & 32));
  }
}

// ---------------------------------------------------------------- layernorm --
__global__ __launch_bounds__(256) void ln_kernel(
    const float* __restrict__ q, const float* __restrict__ k, const float* __restrict__ v,
    const float* __restrict__ gamma, const float* __restrict__ beta,
    unsigned short* __restrict__ lnq, unsigned short* __restrict__ lnk,
    unsigned short* __restrict__ lnv) {
  const int row = blockIdx.x, which = blockIdx.y;
  const float* x = (which == 0 ? q : which == 1 ? k : v) + (long)row * 1024;
  unsigned short* y = (which == 0 ? lnq : which == 1 ? lnk : lnv) + (long)row * 1024;
  const int t = threadIdx.x, lane = t & 63, wv = t >> 6;
  float4 xv = ((const float4*)x)[t];
  float s = xv.x + xv.y + xv.z + xv.w;
  float s2 = xv.x * xv.x + xv.y * xv.y + xv.z * xv.z + xv.w * xv.w;
#pragma unroll
  for (int off = 32; off > 0; off >>= 1) {
    s += __shfl_down(s, off);
    s2 += __shfl_down(s2, off);
  }
  __shared__ float red[8];
  if (lane == 0) { red[wv] = s; red[wv + 4] = s2; }
  __syncthreads();
  float tot = red[0] + red[1] + red[2] + red[3];
  float tot2 = red[4] + red[5] + red[6] + red[7];
  float mu = tot * (1.0f / 1024.0f);
  float var = tot2 * (1.0f / 1024.0f) - mu * mu;
  float rs = rsqrtf(var + 1e-5f);
  float4 g = ((const float4*)gamma)[t];
  float4 be = ((const float4*)beta)[t];
  ushort4 o;
  o.x = f2bf((xv.x - mu) * rs * g.x + be.x);
  o.y = f2bf((xv.y - mu) * rs * g.y + be.y);
  o.z = f2bf((xv.z - mu) * rs * g.z + be.z);
  o.w = f2bf((xv.w - mu) * rs * g.w + be.w);
  ((ushort4*)y)[t] = o;
}

// ---------------------------------------------------------------- GEMM -------
template <int BM, int MODE>
__global__ __launch_bounds__(256) void gemm_kernel(
    const unsigned short* __restrict__ A0, const unsigned short* __restrict__ A1,
    const unsigned short* __restrict__ A2, const unsigned short* __restrict__ Wt,
    const float* __restrict__ b0, const float* __restrict__ b1,
    const float* __restrict__ b2, unsigned short* __restrict__ outB,
    float* __restrict__ outF) {
  constexpr int BK = 64;
  constexpr int MI = BM / 32;
  const int z = blockIdx.z;
  const unsigned short* A = z == 0 ? A0 : z == 1 ? A1 : A2;
  const unsigned short* Bt = Wt + (long)z * 1048576;
  const float* bias = z == 0 ? b0 : z == 1 ? b1 : b2;
  unsigned short* outz = outB + (long)z * 4194304;

  __shared__ char lds[BM * 128 + 16384];
  char* As = lds;
  char* Bs = lds + BM * 128;
  const int tid = threadIdx.x, lane = tid & 63, w = tid >> 6;
  const int wr = w >> 1, wc = w & 1;
  const int m0 = blockIdx.x * BM, n0 = blockIdx.y * 128;
  constexpr int K = 1024;
  constexpr int ACH = BM * 8 / 256;

  f32x4 acc[MI][4] = {};
  for (int kt = 0; kt < K / BK; ++kt) {
    __syncthreads();
#pragma unroll
    for (int i = 0; i < ACH; ++i) {
      int c = tid + i * 256;
      int row = c >> 3, pg = (c & 7) ^ (row & 7);
      gload16(A + (long)(m0 + row) * K + kt * BK + pg * 8, As + c * 16);
    }
#pragma unroll
    for (int i = 0; i < 4; ++i) {
      int c = tid + i * 256;
      int row = c >> 3, pg = (c & 7) ^ (row & 7);
      gload16(Bt + (long)(n0 + row) * K + kt * BK + pg * 8, Bs + c * 16);
    }
    asm volatile("s_waitcnt vmcnt(0)" ::: "memory");
    __syncthreads();
#pragma unroll
    for (int ks = 0; ks < 2; ++ks) {
      short8 af[MI], bf[4];
#pragma unroll
      for (int mi = 0; mi < MI; ++mi) {
        int row = wr * (BM / 2) + mi * 16 + (lane & 15);
        int part = (ks * 4 + (lane >> 4)) ^ (row & 7);
        af[mi] = *(const short8*)(As + row * 128 + part * 16);
      }
#pragma unroll
      for (int ni = 0; ni < 4; ++ni) {
        int row = wc * 64 + ni * 16 + (lane & 15);
        int part = (ks * 4 + (lane >> 4)) ^ (row & 7);
        bf[ni] = *(const short8*)(Bs + row * 128 + part * 16);
      }
#pragma unroll
      for (int mi = 0; mi < MI; ++mi)
#pragma unroll
        for (int ni = 0; ni < 4; ++ni)
          acc[mi][ni] = MFMA16(af[mi], bf[ni], acc[mi][ni]);
    }
  }
#pragma unroll
  for (int mi = 0; mi < MI; ++mi) {
    int mbase = m0 + wr * (BM / 2) + mi * 16 + ((lane >> 4) << 2);
#pragma unroll
    for (int ni = 0; ni < 4; ++ni) {
      int j = n0 + wc * 64 + ni * 16 + (lane & 15);
      float bj = bias[j];
#pragma unroll
      for (int r = 0; r < 4; ++r) {
        float vv = acc[mi][ni][r] + bj;
        int mm = mbase + r;
        if (MODE == 0) {
          int b = mm >> 11, s = mm & 2047;
          int h = j >> 6, d = j & 63;
          outz[(((long)(b * 16 + h)) * 2048 + s) * 64 + d] = f2bf(vv);
        } else {
          outF[(long)mm * 1024 + j] = vv;
        }
      }
    }
  }
}

// ---------------------------------------------------------------- V transpose
__global__ __launch_bounds__(256) void vtrans_kernel(const unsigned short* __restrict__ vh,
                                                     unsigned short* __restrict__ vt) {
  const int bh = blockIdx.y, s0 = blockIdx.x * 64;
  const unsigned short* in = vh + (long)bh * 2048 * 64;
  unsigned short* out = vt + (long)bh * 64 * 2048;
  __shared__ unsigned short lds[64][72];
  const int t = threadIdx.x;
#pragma unroll
  for (int i = 0; i < 2; ++i) {
    int c = t + i * 256;
    int sl = c >> 3, p = c & 7;
    short8 vv = *(const short8*)(in + (long)(s0 + sl) * 64 + p * 8);
#pragma unroll
    for (int j = 0; j < 8; ++j) lds[sl][p * 8 + j] = (unsigned short)vv[j];
  }
  __syncthreads();
#pragma unroll
  for (int i = 0; i < 4; ++i) {
    int c = t + i * 256;
    int d = c >> 4, s4 = (c & 15) * 4;
    ushort4 o;
    o.x = lds[s4][d]; o.y = lds[s4 + 1][d]; o.z = lds[s4 + 2][d]; o.w = lds[s4 + 3][d];
    *(ushort4*)(out + (long)d * 2048 + s0 + s4) = o;
  }
}

// ---------------------------------------------------------------- attention --
// Swapped-QK^T flash attention, fixed-max softmax (no rescale), KVBLK=64,
// double-buffered K/V staging with counted vmcnt, 16 q-rows per wave.
// qh,kh [BH][2048][64] bf16; vt [BH][64][2048] bf16; mbits [B][2048][64] u32
__global__ __launch_bounds__(256, 4) void attn_kernel(
    const unsigned short* __restrict__ qh, const unsigned short* __restrict__ kh,
    const unsigned short* __restrict__ vt, const unsigned* __restrict__ mbits,
    unsigned short* __restrict__ O) {
  constexpr int S = 2048, NT = 32;
  __shared__ char lds[40960];  // K dbuf 16K | V dbuf 16K | P 4x2K
  char* Ks = lds;
  char* Vts = lds + 16384;
  const int tid = threadIdx.x, lane = tid & 63, w = tid >> 6;
  const int g = lane >> 4, c = lane & 15;
  char* Pw = lds + 32768 + w * 2048;  // [16 q][128B]

  // XCD-bijective swizzle: 1024 blocks -> 4 contiguous heads per XCD
  const int flat = blockIdx.y * 32 + blockIdx.x;
  const int fl2 = (flat & 7) * 128 + (flat >> 3);
  const int qb = fl2 & 31, bh = fl2 >> 5, b = bh >> 4;

  const unsigned short* qp = qh + (long)bh * S * 64;
  const unsigned short* kp = kh + (long)bh * S * 64;
  const unsigned short* vp = vt + (long)bh * 64 * S;
  unsigned short* op = O + (long)bh * S * 64;
  const unsigned* mrow = mbits + (long)b * S * 64;
  const int q0 = qb * 64 + w * 16;
  const int myq = q0 + c;

  // Q as B-frags: B[col=q=c][d = ds*32 + g*8 .. +7]
  short8 bq_[2];
#pragma unroll
  for (int ds = 0; ds < 2; ++ds)
    bq_[ds] = *(const short8*)(qp + (long)myq * 64 + ds * 32 + g * 8);

  f32x4 o_acc[4] = {};
  float lpart = 0.f;

#define STAGE(KT, BUF)                                                          \
  {                                                                             \
    _Pragma("unroll") for (int i = 0; i < 2; ++i) {                             \
      int cc = tid + i * 256;                                                   \
      int row = cc >> 3, pg = (cc & 7) ^ (row & 7);                             \
      gload16(kp + (long)((KT)*64 + row) * 64 + pg * 8, Ks + (BUF)*8192 + cc * 16); \
    }                                                                           \
    _Pragma("unroll") for (int i = 0; i < 2; ++i) {                             \
      int cc = tid + i * 256;                                                   \
      int row = cc >> 3, pg = (cc & 7) ^ (row & 7);                             \
      gload16(vp + (long)row * S + (KT)*64 + pg * 8, Vts + (BUF)*8192 + cc * 16); \
    }                                                                           \
  }

  STAGE(0, 0);
  uint2 mcur = *(const uint2*)(mrow + (long)myq * 64);
  uint2 mnxt = mcur;

  for (int kt = 0; kt < NT; ++kt) {
    const int cur = kt & 1;
    if (kt + 1 < NT) {
      STAGE(kt + 1, cur ^ 1);
      mnxt = *(const uint2*)(mrow + (long)myq * 64 + (kt + 1) * 2);
      asm volatile("s_waitcnt vmcnt(4)" ::: "memory");
    } else {
      asm volatile("s_waitcnt vmcnt(0)" ::: "memory");
    }
    __builtin_amdgcn_s_barrier();

    // QK^T (swapped): sc[kf] rows = k-local, cols = q
    f32x4 sc[4] = {};
    const char* Kb = Ks + cur * 8192;
    __builtin_amdgcn_s_setprio(1);
#pragma unroll
    for (int ds = 0; ds < 2; ++ds) {
#pragma unroll
      for (int kf = 0; kf < 4; ++kf) {
        int row = kf * 16 + c;
        int part = (ds * 4 + g) ^ (row & 7);
        short8 ak = *(const short8*)(Kb + row * 128 + part * 16);
        sc[kf] = MFMA16(ak, bq_[ds], sc[kf]);
      }
    }
    __builtin_amdgcn_s_setprio(0);

    // softmax (fixed-max): p = live ? exp2(s * 0.125 * log2e) : 0
    unsigned ws0 = mcur.x >> (g * 4), ws1 = mcur.y >> (g * 4);
#pragma unroll
    for (int kf = 0; kf < 4; ++kf) {
      unsigned wsh = ((kf >= 2) ? ws1 : ws0) >> ((kf & 1) * 16);
      float pv[4];
#pragma unroll
      for (int r = 0; r < 4; ++r) {
        float p = exp2f(sc[kf][r] * (0.125f * LOG2E));
        p = ((wsh >> r) & 1u) ? p : 0.f;
        lpart += p;
        pv[r] = p;
      }
      unsigned lo = (unsigned)f2bf(pv[0]) | ((unsigned)f2bf(pv[1]) << 16);
      unsigned hi = (unsigned)f2bf(pv[2]) | ((unsigned)f2bf(pv[3]) << 16);
      int plog = kf * 2 + (g >> 1);
      uint2 pk; pk.x = lo; pk.y = hi;
      *(uint2*)(Pw + c * 128 + ((plog ^ (c & 7)) * 16) + (g & 1) * 8) = pk;
    }
    mcur = mnxt;

    // PV
    const char* Vb = Vts + cur * 8192;
    __builtin_amdgcn_s_setprio(1);
#pragma unroll
    for (int ks = 0; ks < 2; ++ks) {
      int part = ks * 4 + g;
      short8 pa = *(const short8*)(Pw + c * 128 + ((part ^ (c & 7)) * 16));
#pragma unroll
      for (int nd = 0; nd < 4; ++nd) {
        int d = nd * 16 + c;
        short8 bv = *(const short8*)(Vb + d * 128 + ((part ^ (d & 7)) * 16));
        o_acc[nd] = MFMA16(pa, bv, o_acc[nd]);
      }
    }
    __builtin_amdgcn_s_setprio(0);

    // drain LDS reads before barrier so next stage can't overwrite in-flight
    asm volatile("s_waitcnt lgkmcnt(0)" ::: "memory");
    __builtin_amdgcn_sched_barrier(0);
    __builtin_amdgcn_s_barrier();
  }
#undef STAGE

  // epilogue: reduce l across the 4 g-groups, divide, store
  lpart += __shfl_xor(lpart, 16);
  lpart += __shfl_xor(lpart, 32);
#pragma unroll
  for (int r = 0; r < 4; ++r) {
    float lr = __shfl(lpart, g * 4 + r);
    float inv = 1.0f / lr;
    int qrow = q0 + g * 4 + r;
#pragma unroll
    for (int nd = 0; nd < 4; ++nd)
      op[(long)qrow * 64 + nd * 16 + c] = f2bf(o_acc[nd][r] * inv);
  }
}

// ---------------------------------------------------------------- launch -----
extern "C" void kernel_launch(void* const* d_in, const int* in_sizes, int n_in,
                              void* d_out, int out_size, void* d_ws, size_t ws_size,
                              hipStream_t stream) {
  const float* q = (const float*)d_in[0];
  const float* k = (const float*)d_in[1];
  const float* v = (const float*)d_in[2];
  const int* mask = (const int*)d_in[3];
  const float* Wq = (const float*)d_in[4];
  const float* bq = (const float*)d_in[5];
  const float* Wk = (const float*)d_in[6];
  const float* bk = (const float*)d_in[7];
  const float* Wv = (const float*)d_in[8];
  const float* bv = (const float*)d_in[9];
  const float* Wo = (const float*)d_in[10];
  const float* bo = (const float*)d_in[11];
  const float* gamma = (const float*)d_in[12];
  const float* beta = (const float*)d_in[13];
  float* out = (float*)d_out;

  char* ws = (char*)d_ws;
  unsigned short* Wt = (unsigned short*)ws;                         // 8 MB
  unsigned* mbits = (unsigned*)(ws + 8u * 1024 * 1024);             // 1 MB
  unsigned short* lnq = (unsigned short*)(ws + 9u * 1024 * 1024);   // 8 MB
  unsigned short* lnk = lnq + 4194304;
  unsigned short* lnv = lnk + 4194304;
  unsigned short* qh = lnv + 4194304;
  unsigned short* kh = qh + 4194304;
  unsigned short* vh = kh + 4194304;
  unsigned short* vtb = lnk;  // alias: lnk dead after QKV GEMM
  unsigned short* Ob = lnq;   // alias: lnq dead after QKV GEMM

  wtrans_kernel<<<dim3(16, 16, 4), 256, 0, stream>>>(Wq, Wk, Wv, Wo, Wt);
  maskpack_kernel<<<1024, 256, 0, stream>>>(mask, mbits);
  ln_kernel<<<dim3(4096, 3), 256, 0, stream>>>(q, k, v, gamma, beta, lnq, lnk, lnv);
  gemm_kernel<128, 0><<<dim3(32, 8, 3), 256, 0, stream>>>(lnq, lnk, lnv, Wt, bq, bk, bv,
                                                          qh, nullptr);
  vtrans_kernel<<<dim3(32, 32), 256, 0, stream>>>(vh, vtb);
  attn_kernel<<<dim3(32, 32), 256, 0, stream>>>(qh, kh, vtb, mbits, Ob);
  gemm_kernel<64, 1><<<dim3(64, 8, 1), 256, 0, stream>>>(Ob, Ob, Ob, Wt + 3 * 1048576,
                                                         bo, bo, bo, nullptr, out);
}